// Round 4
// baseline (103.857 us; speedup 1.0000x reference)
//
#include <hip/hip_runtime.h>
#include <math.h>

#define P      512
#define NA     180
#define NB     4
#define FOFF4  64               // leading zero-pad floats per angle row (16 positions x 4 batches)
#define FS4    (FOFF4 + 4 * P + FOFF4)   // 2176 floats: pad + 4-batch-interleaved data + pad
#define GUARD  512              // float guard before fil2 for window underreach (LDS stage + global taps)
#define TS     16               // backprojection pixel tile (16x16 -> 1024 blocks, 4/CU)
#define WPOS   28               // window positions per angle
#define WSF4   (WPOS * 4)       // 112 floats per angle (28 positions x 4 batches)
#define ASEG   60               // angles per segment round (3 segments)
#define LDSN   36               // per segment: first 36 angles via LDS window...
                                // ...remaining 24 via direct global taps (L1 pipe)
#define NTILES (32 * 32)

#if __has_builtin(__builtin_amdgcn_fractf)
#define FRACT(x) __builtin_amdgcn_fractf(x)
#else
#define FRACT(x) ((x) - floorf(x))
#endif

typedef float f4 __attribute__((ext_vector_type(4), aligned(16)));

// ===========================================================================
// Compile-time tables (unchanged from r3): hr (Shepp-Logan ramp impulse
// response) and the angle sin/cos table are input-independent constexpr
// __constant__ data. f64 Taylor sin/cos (quarter-wave reduced) ~1 ulp.
// ===========================================================================
constexpr double PI_D = 3.14159265358979323846264338327950288;

struct D512 { double v[512]; };
struct F512 { float v[512]; };
struct SCT2 { float sc[NA][2]; };

constexpr double cosap(double x) {   // |x| <= ~pi/2, Taylor to x^24
    double invf[13] = {};
    double f = 1.0; invf[0] = 1.0;
    for (int n = 1; n <= 12; ++n) { f *= (double)((2 * n - 1) * (2 * n)); invf[n] = 1.0 / f; }
    const double x2 = x * x;
    double r = invf[12];
    for (int n = 11; n >= 0; --n) r = invf[n] - x2 * r;
    return r;
}
constexpr double sinap(double x) {   // |x| <= ~pi/2, Taylor to x^25
    double invf[13] = {};
    double f = 1.0; invf[0] = 1.0;
    for (int n = 1; n <= 12; ++n) { f *= (double)((2 * n) * (2 * n + 1)); invf[n] = 1.0 / f; }
    const double x2 = x * x;
    double r = invf[12];
    for (int n = 11; n >= 0; --n) r = invf[n] - x2 * r;
    return x * r;
}

constexpr D512 make_ct() {           // cos(2*pi*ph/512), quarter-wave reduced
    D512 t{};
    for (int ph = 0; ph < 512; ++ph) {
        const int q = ph >> 7, r = ph & 127;
        double v = 0.0;
        if (q == 0)      v =  cosap(PI_D * (double)r / 256.0);
        else if (q == 1) v = -cosap(PI_D * (double)(128 - r) / 256.0);
        else if (q == 2) v = -cosap(PI_D * (double)r / 256.0);
        else             v =  cosap(PI_D * (double)(128 - r) / 256.0);
        t.v[ph] = v;
    }
    return t;
}
constexpr D512 CT = make_ct();

constexpr F512 make_ffg() {
    F512 t{};
    double fv[128] = {};
    for (int mm = 0; mm < 128; ++mm) {
        const double pn = PI_D * (double)(2 * mm + 1);
        fv[mm] = -1.0 / (pn * pn);
    }
    for (int o = 0; o <= 256; ++o) {
        double s = 0.0;
        for (int mm = 0; mm < 128; ++mm)
            s += fv[mm] * CT.v[(o * (2 * mm + 1)) & 511];
        double ff = 0.5 + 4.0 * s;           // 0.5 + 2*(2*s_half)
        if (o > 0) {
            const double w = PI_D * (double)o / 512.0;
            ff *= sinap(w) / w;
        }
        t.v[o] = (float)ff;
    }
    for (int o = 257; o < 512; ++o) t.v[o] = t.v[512 - o];
    return t;
}
constexpr F512 FFG = make_ffg();

constexpr F512 make_hr_part(int lo, int hi) {
    F512 t{};
    for (int o = lo; o < hi; ++o) {
        double s2 = 0.0;
        for (int k = 1; k < 256; ++k)
            s2 += (double)FFG.v[k] * CT.v[(o * k) & 511];
        double s = (double)FFG.v[0] + (double)FFG.v[256] * CT.v[(o * 256) & 511] + 2.0 * s2;
        t.v[o] = (float)(s / 512.0);
    }
    return t;
}
constexpr F512 HR_A = make_hr_part(0, 129);
constexpr F512 HR_B = make_hr_part(129, 257);

constexpr F512 make_hr() {
    F512 t{};
    for (int o = 0; o < 129; ++o)   t.v[o] = HR_A.v[o];
    for (int o = 129; o < 257; ++o) t.v[o] = HR_B.v[o];
    for (int o = 257; o < 512; ++o) t.v[o] = t.v[512 - o];
    return t;
}
__constant__ F512 HRC = make_hr();

constexpr SCT2 make_sct() {
    SCT2 t{};
    for (int a = 0; a < NA; ++a) {
        const float thf = (float)a * (float)(PI_D / 179.0);
        const double x = (double)thf;        // in [0, ~pi]
        double sv, cv;
        if (x <= PI_D * 0.5) { sv = sinap(x);        cv =  cosap(x); }
        else                 { sv = sinap(PI_D - x); cv = -cosap(PI_D - x); }
        t.sc[a][0] = (float)sv;
        t.sc[a][1] = (float)cv;
    }
    return t;
}
__constant__ SCT2 SCT = make_sct();

// ---------------------------------------------------------------------------
// K2: one 512-thread block per angle: circular conv for ALL 4 batches with
// hr from __constant__ (s_loads), rolling register window -> ONE ds_read_b128
// per K-step per thread. Output 4-batch interleaved (FOFF4 + 4*pos + b),
// staged through LDS so global stores are coalesced dwordx4. The window-base
// table build (qbt) is fused into the tail of the same blocks.
// ---------------------------------------------------------------------------
__global__ __launch_bounds__(512) void ir_filter(const float* __restrict__ sino,
                                                 float* __restrict__ fil2,
                                                 float* __restrict__ qbt) {
    __shared__ __align__(16) float row2[4][2 * P];
    __shared__ __align__(16) float sOut[4 * P];
    const int a = blockIdx.x;
    const int t = threadIdx.x;

    const int b = t >> 7;             // batch 0..3
    const int tt = t & 127;           // outputs 4tt..4tt+3

    const float* src = sino + ((size_t)b * NA + a) * P;
    const float4 v = *(const float4*)(src + 4 * tt);
    *(float4*)&row2[b][4 * tt] = v;
    *(float4*)&row2[b][4 * tt + P] = v;
    __syncthreads();

    const int base0 = P + 4 * tt;
    float4 A = *(const float4*)&row2[b][base0];    // window floats w[0..3]
    float a0 = 0.f, a1 = 0.f, a2 = 0.f, a3 = 0.f;
    #pragma unroll 4
    for (int J = 0; J < P; J += 4) {
        const float4 Bv = *(const float4*)&row2[b][base0 - J - 4];  // w[-4..-1]
        const float h0 = HRC.v[J], h1 = HRC.v[J + 1], h2v = HRC.v[J + 2], h3 = HRC.v[J + 3];
        a0 = fmaf(h0, A.x, a0); a0 = fmaf(h1, Bv.w, a0); a0 = fmaf(h2v, Bv.z, a0); a0 = fmaf(h3, Bv.y, a0);
        a1 = fmaf(h0, A.y, a1); a1 = fmaf(h1, A.x, a1); a1 = fmaf(h2v, Bv.w, a1); a1 = fmaf(h3, Bv.z, a1);
        a2 = fmaf(h0, A.z, a2); a2 = fmaf(h1, A.y, a2); a2 = fmaf(h2v, A.x, a2); a2 = fmaf(h3, Bv.w, a2);
        a3 = fmaf(h0, A.w, a3); a3 = fmaf(h1, A.z, a3); a3 = fmaf(h2v, A.y, a3); a3 = fmaf(h3, A.x, a3);
        A = Bv;                                    // slide the register window
    }
    // interleave via LDS: float index in data region = 4*pos + b, pos = 4tt+d
    const int o0 = 16 * tt + b;
    sOut[o0]      = a0;
    sOut[o0 + 4]  = a1;
    sOut[o0 + 8]  = a2;
    sOut[o0 + 12] = a3;
    __syncthreads();

    float* frow = fil2 + (size_t)a * FS4;
    *(f4*)(frow + FOFF4 + 4 * t) = *(const f4*)(sOut + 4 * t);   // coalesced
    if (t < FOFF4) {                  // zero pads (ws re-poisoned every call)
        frow[t] = 0.f;
        frow[FOFF4 + 4 * P + t] = 0.f;
    }

    // fused window-base table for this angle
    const float sa = SCT.sc[a][0];
    const float ca = SCT.sc[a][1];
    #pragma unroll
    for (int i = 0; i < 2; ++i) {
        const int tile = t + 512 * i;          // by*32+bx
        const int bx = tile & 31, by = tile >> 5;
        const float xlo = (float)(240 - 16 * bx);   // min x over tile
        const float ylo = (float)(16 * by - 256);
        const float yhi = (float)(16 * by - 241);
        const float pmin = fmaf(sa, xlo, fminf(ca * ylo, ca * yhi) + 256.0f);
        const int base = ((int)floorf(pmin) - 2) & ~1;  // even, fp-slop safety
        qbt[tile * NA + a] = (float)(256 - base);
    }
}

// ---------------------------------------------------------------------------
// K3: backprojection, ALL 4 BATCHES per block, 16x16 tile (1024 blocks).
// DUAL-PIPE taps: per 60-angle segment, the first LDSN=36 angles read their
// windows from a staged LDS buffer (ds_read_b128 pair), the remaining 24
// read DIRECTLY from global (dwordx4 pair; fil2 is L2-resident and each
// tile's per-angle window is L1-hot) -- LDS and L1 are independent pipes,
// so tap bandwidth is their SUM instead of LDS alone. base_a is derived
// from the SAME qrow value as q, so j/fr/taps and the 0..179 accumulation
// order are bit-identical to the all-LDS version.
// ---------------------------------------------------------------------------
__global__ __launch_bounds__(256) void ir_backproject(const float* __restrict__ fil2,
                                                      const float* __restrict__ qbt,
                                                      float* __restrict__ out) {
    __shared__ __align__(16) float win[LDSN * WSF4 + 16];   // 16.2 KB + slack

    const int t = threadIdx.x;
    const int w0 = blockIdx.x * TS, h0 = blockIdx.y * TS;
    const float* qrow = qbt + (blockIdx.y * 32 + blockIdx.x) * NA;  // this tile's bases

    const int w = w0 + (t & 15);
    const int h = h0 + (t >> 4);

    const int ix = 255 - w;              // reversed x axis
    const int iy = h - 256;
    const int m = (ix * ix + iy * iy) <= 256 * 256;

    float* o0 = out + (size_t)h * P + w;

    if (__syncthreads_count(m) == 0) {   // tile fully outside circle
        o0[0] = 0.f;
        o0[P * P] = 0.f;
        o0[2 * P * P] = 0.f;
        o0[3 * P * P] = 0.f;
        return;
    }

    const float xf = (float)ix;
    const float yf = (float)iy;
    float acc0 = 0.f, acc1 = 0.f, acc2 = 0.f, acc3 = 0.f;

    #pragma unroll
    for (int seg = 0; seg < 3; ++seg) {
        const int A0 = seg * ASEG;

        // Phase B: stage the segment's first LDSN angle windows (16B chunks)
        for (int idx = t; idx < LDSN * WPOS; idx += 256) {
            const int al = idx / WPOS;
            const int i = idx - al * WPOS;
            const int a = A0 + al;
            const int base = 256 - (int)qrow[a];          // lane-varying -> v-load
            const int off = a * FS4 + FOFF4 + 4 * (base + i);  // 16B aligned
            const f4 vv = *(const f4*)(fil2 + off);
            *(f4*)(win + al * WSF4 + 4 * i) = vv;
        }
        __syncthreads();

        // Phase C1: LDS-pipe angles. f4 at 4j = 4 batches at position j.
        #pragma unroll 4
        for (int al = 0; al < LDSN; ++al) {
            const float ss = SCT.sc[A0 + al][0];          // wave-uniform -> s_load
            const float cc = SCT.sc[A0 + al][1];
            const float qb = qrow[A0 + al];               // wave-uniform -> s_load
            const float q = fmaf(xf, ss, fmaf(yf, cc, qb));
            const int j = (int)q;
            const float fr = FRACT(q);
            const float omf = 1.f - fr;
            const f4 W0 = *(const f4*)(win + al * WSF4 + 4 * j);
            const f4 W1 = *(const f4*)(win + al * WSF4 + 4 * j + 4);
            acc0 = fmaf(omf, W0.x, fmaf(fr, W1.x, acc0));
            acc1 = fmaf(omf, W0.y, fmaf(fr, W1.y, acc1));
            acc2 = fmaf(omf, W0.z, fmaf(fr, W1.z, acc2));
            acc3 = fmaf(omf, W0.w, fmaf(fr, W1.w, acc3));
        }

        // Phase C2: L1-pipe angles -- direct global taps, same j/fr/taps.
        #pragma unroll 4
        for (int al = LDSN; al < ASEG; ++al) {
            const int a = A0 + al;
            const float ss = SCT.sc[a][0];
            const float cc = SCT.sc[a][1];
            const float qb = qrow[a];                     // wave-uniform -> s_load
            const float q = fmaf(xf, ss, fmaf(yf, cc, qb));
            const int j = (int)q;
            const float fr = FRACT(q);
            const float omf = 1.f - fr;
            const int base_a = 256 - (int)qb;             // same source as q -> bit-identical
            const float* gp = fil2 + a * FS4 + FOFF4 + 4 * base_a;
            const f4 W0 = *(const f4*)(gp + 4 * j);
            const f4 W1 = *(const f4*)(gp + 4 * j + 4);
            acc0 = fmaf(omf, W0.x, fmaf(fr, W1.x, acc0));
            acc1 = fmaf(omf, W0.y, fmaf(fr, W1.y, acc1));
            acc2 = fmaf(omf, W0.z, fmaf(fr, W1.z, acc2));
            acc3 = fmaf(omf, W0.w, fmaf(fr, W1.w, acc3));
        }
        if (seg < 2) __syncthreads();    // protect win before restage (uniform)
    }

    const float scale = (float)(M_PI / (2.0 * NA));
    o0[0]         = m ? acc0 * scale : 0.f;
    o0[P * P]     = m ? acc1 * scale : 0.f;
    o0[2 * P * P] = m ? acc2 * scale : 0.f;
    o0[3 * P * P] = m ? acc3 * scale : 0.f;
}

// ---------------------------------------------------------------------------
extern "C" void kernel_launch(void* const* d_in, const int* in_sizes, int n_in,
                              void* d_out, int out_size, void* d_ws, size_t ws_size,
                              hipStream_t stream) {
    const float* sino = (const float*)d_in[0];
    float* out = (float*)d_out;
    float* ws = (float*)d_ws;

    float* qbt   = ws;                        // 1024 tiles * 180 floats
    float* fil2  = ws + NTILES * NA + GUARD;  // 180*2176 floats, 16B aligned

    ir_filter<<<NA, 512, 0, stream>>>(sino, fil2, qbt);

    dim3 gridB(P / TS, P / TS, 1);            // 1024 blocks, 4 batches in-block
    ir_backproject<<<gridB, 256, 0, stream>>>(fil2, qbt, out);
}